// Round 4
// baseline (43.571 us; speedup 1.0000x reference)
//
#include <hip/hip_runtime.h>

// PROBE ROUND: identical R3 kernel, dispatched TWICE in the same graph.
// Second dispatch recomputes the same output (deterministic, validates).
// Purpose: split fixed per-replay overhead from true kernel time:
//   dur2 - dur1_prev(25.5) ~= warm kernel time; 25.5 - that ~= fixed overhead.

#define MIN3(a, b, c) fminf(fminf(a, b), c)
#define MAX3(a, b, c) fmaxf(fmaxf(a, b), c)
#define MED3(a, b, c) __builtin_amdgcn_fmed3f(a, b, c)

constexpr int H = 512, W = 512;
constexpr int RPS = 8;                 // rows per strip (per thread)
constexpr int NBLOCKS = (16 * 3 * H / RPS) * 2;  // 6144

__device__ __forceinline__ void load_row(const float* __restrict__ rowp, int x0,
                                         int lane, bool valid, float v[6]) {
    if (valid) {
        const float4 q = *reinterpret_cast<const float4*>(rowp + x0);
        float lft = __shfl_up(q.w, 1);    // lane i-1's col x0-1
        float rgt = __shfl_down(q.x, 1);  // lane i+1's col x0+4
        if (lane == 0)  lft = (x0 > 0)     ? rowp[x0 - 1] : 0.0f;
        if (lane == 63) rgt = (x0 + 4 < W) ? rowp[x0 + 4] : 0.0f;
        v[0] = lft; v[1] = q.x; v[2] = q.y; v[3] = q.z; v[4] = q.w; v[5] = rgt;
    } else {
        v[0] = v[1] = v[2] = 0.0f;
        v[3] = v[4] = v[5] = 0.0f;
    }
}

__global__ __launch_bounds__(64) void median3x3_kernel(
    const float* __restrict__ in, float* __restrict__ out) {
    const int braw = blockIdx.x;
    const int bid = (braw & 7) * (NBLOCKS / 8) + (braw >> 3);

    const int half = bid & 1;
    const int strip = bid >> 1;
    const int lane = threadIdx.x;
    const int x0 = half * 256 + (lane << 2);

    const int rg0 = strip * RPS;
    const int plane = rg0 >> 9;
    const int y0 = rg0 & (H - 1);

    const float* base = in + (size_t)plane * H * W;
    float* obase = out + (size_t)plane * H * W;

    float c0[6], c1[6], c2[6];
    load_row(base + (size_t)(y0 - 1) * W, x0, lane, y0 > 0, c0);
    load_row(base + (size_t)y0 * W, x0, lane, true, c1);

#pragma unroll
    for (int r = 0; r < RPS; ++r) {
        const int yn = y0 + r + 1;
        load_row(base + (size_t)yn * W, x0, lane, yn < H, c2);

        float lo[6], mi[6], hi[6];
#pragma unroll
        for (int j = 0; j < 6; ++j) {
            lo[j] = MIN3(c0[j], c1[j], c2[j]);
            mi[j] = MED3(c0[j], c1[j], c2[j]);
            hi[j] = MAX3(c0[j], c1[j], c2[j]);
        }

        float res[4];
#pragma unroll
        for (int k = 0; k < 4; ++k) {
            const float a = MAX3(lo[k], lo[k + 1], lo[k + 2]);
            const float b = MED3(mi[k], mi[k + 1], mi[k + 2]);
            const float c = MIN3(hi[k], hi[k + 1], hi[k + 2]);
            res[k] = MED3(a, b, c);
        }
        float4 o;
        o.x = res[0]; o.y = res[1]; o.z = res[2]; o.w = res[3];
        *reinterpret_cast<float4*>(obase + (size_t)(y0 + r) * W + x0) = o;

#pragma unroll
        for (int j = 0; j < 6; ++j) { c0[j] = c1[j]; c1[j] = c2[j]; }
    }
}

extern "C" void kernel_launch(void* const* d_in, const int* in_sizes, int n_in,
                              void* d_out, int out_size, void* d_ws, size_t ws_size,
                              hipStream_t stream) {
    const float* x = (const float*)d_in[0];
    float* out = (float*)d_out;
    // PROBE: two identical dispatches (second overwrites the first).
    median3x3_kernel<<<NBLOCKS, 64, 0, stream>>>(x, out);
    median3x3_kernel<<<NBLOCKS, 64, 0, stream>>>(x, out);
}

// Round 5
// 22.468 us; speedup vs baseline: 1.9393x; 1.9393x over previous
//
#include <hip/hip_runtime.h>

// 3x3 median blur, float32, B=16 C=3 H=512 W=512, zero padding.
// One wave (64 lanes) per block; each lane computes 4 cols x 16 rows
// (rolling register window: 18 rows loaded per 16 produced -> 1.125x fetch).
// Halo columns via cross-lane shuffles; lanes 0/63 do predicated edge loads.
// Median of 9 = med3( max3(lo), med3(mid), min3(hi) ) over vertically
// sorted column triples (v_min3/v_med3/v_max3, 1 instr each).
//
// R4 probe established: fixed per-replay overhead ~7.5us; kernel proper runs
// at ~6.3 TB/s = the measured achievable device BW (m13). This is the
// roofline configuration.

#define MIN3(a, b, c) fminf(fminf(a, b), c)
#define MAX3(a, b, c) fmaxf(fmaxf(a, b), c)
#define MED3(a, b, c) __builtin_amdgcn_fmed3f(a, b, c)

constexpr int H = 512, W = 512;
constexpr int RPS = 16;                          // rows per strip (per thread)
constexpr int NBLOCKS = (16 * 3 * H / RPS) * 2;  // 1536 strips * 2 halves = 3072

__device__ __forceinline__ void load_row(const float* __restrict__ rowp, int x0,
                                         int lane, bool valid, float v[6]) {
    if (valid) {
        const float4 q = *reinterpret_cast<const float4*>(rowp + x0);
        float lft = __shfl_up(q.w, 1);    // lane i-1's col x0-1
        float rgt = __shfl_down(q.x, 1);  // lane i+1's col x0+4
        if (lane == 0)  lft = (x0 > 0)     ? rowp[x0 - 1] : 0.0f;
        if (lane == 63) rgt = (x0 + 4 < W) ? rowp[x0 + 4] : 0.0f;
        v[0] = lft; v[1] = q.x; v[2] = q.y; v[3] = q.z; v[4] = q.w; v[5] = rgt;
    } else {
        v[0] = v[1] = v[2] = 0.0f;
        v[3] = v[4] = v[5] = 0.0f;
    }
}

__global__ __launch_bounds__(64) void median3x3_kernel(
    const float* __restrict__ in, float* __restrict__ out) {
    // Bijective XCD swizzle (3072 % 8 == 0): contiguous chunks per XCD
    const int braw = blockIdx.x;
    const int bid = (braw & 7) * (NBLOCKS / 8) + (braw >> 3);

    const int half = bid & 1;            // which 256-col half of the row
    const int strip = bid >> 1;          // vertical strip id (RPS rows each)
    const int lane = threadIdx.x;        // 0..63
    const int x0 = half * 256 + (lane << 2);

    const int rg0 = strip * RPS;         // first output row (global row index)
    const int plane = rg0 >> 9;          // H = 512; strips never cross planes
    const int y0 = rg0 & (H - 1);

    const float* base = in + (size_t)plane * H * W;
    float* obase = out + (size_t)plane * H * W;

    float c0[6], c1[6], c2[6];
    load_row(base + (size_t)(y0 - 1) * W, x0, lane, y0 > 0, c0);
    load_row(base + (size_t)y0 * W, x0, lane, true, c1);

#pragma unroll
    for (int r = 0; r < RPS; ++r) {
        const int yn = y0 + r + 1;
        load_row(base + (size_t)yn * W, x0, lane, yn < H, c2);

        // vertically sort the 6 columns (3 instrs per column)
        float lo[6], mi[6], hi[6];
#pragma unroll
        for (int j = 0; j < 6; ++j) {
            lo[j] = MIN3(c0[j], c1[j], c2[j]);
            mi[j] = MED3(c0[j], c1[j], c2[j]);
            hi[j] = MAX3(c0[j], c1[j], c2[j]);
        }

        // 4 output pixels, 4 instrs each
        float res[4];
#pragma unroll
        for (int k = 0; k < 4; ++k) {
            const float a = MAX3(lo[k], lo[k + 1], lo[k + 2]);
            const float b = MED3(mi[k], mi[k + 1], mi[k + 2]);
            const float c = MIN3(hi[k], hi[k + 1], hi[k + 2]);
            res[k] = MED3(a, b, c);
        }
        float4 o;
        o.x = res[0]; o.y = res[1]; o.z = res[2]; o.w = res[3];
        *reinterpret_cast<float4*>(obase + (size_t)(y0 + r) * W + x0) = o;

#pragma unroll
        for (int j = 0; j < 6; ++j) { c0[j] = c1[j]; c1[j] = c2[j]; }
    }
}

extern "C" void kernel_launch(void* const* d_in, const int* in_sizes, int n_in,
                              void* d_out, int out_size, void* d_ws, size_t ws_size,
                              hipStream_t stream) {
    const float* x = (const float*)d_in[0];
    float* out = (float*)d_out;
    median3x3_kernel<<<NBLOCKS, 64, 0, stream>>>(x, out);
}